// Round 2
// baseline (432.614 us; speedup 1.0000x reference)
//
#include <hip/hip_runtime.h>
#include <hip/hip_bf16.h>

#define N_SAMPLES 262144
#define NUM_FLOWS 8
#define HIDDEN 64
#define SPT 2                      // samples per thread
#define BLOCK 256
#define NTHREADS (N_SAMPLES / SPT) // 131072
#define NBLOCKS (NTHREADS / BLOCK) // 512

__device__ __forceinline__ float b2f(__hip_bfloat16 x) { return __bfloat162float(x); }

// dtype-flexible load/store: f32 flag is uniform across the grid (sniffed from
// L_tril's structurally-zero upper-triangle element).
__device__ __forceinline__ float ldv(const void* p, int i, bool f32) {
    return f32 ? ((const float*)p)[i] : b2f(((const __hip_bfloat16*)p)[i]);
}
__device__ __forceinline__ void stv(void* p, int i, float v, bool f32) {
    if (f32) ((float*)p)[i] = v;
    else ((__hip_bfloat16*)p)[i] = __float2bfloat16(v);
}

__global__ __launch_bounds__(BLOCK, 2) void glow_kernel(
    const void* __restrict__ g_eps,
    const void* __restrict__ g_L_tril,
    const void* __restrict__ g_base_mean,
    const void* __restrict__ g_an_log_scale,
    const void* __restrict__ g_an_shift,
    const void* __restrict__ g_perm_p,
    const void* __restrict__ g_sign_s,
    const void* __restrict__ g_lu_l,
    const void* __restrict__ g_lu_u,
    const void* __restrict__ g_lu_log_s,
    const void* __restrict__ g_W1,
    const void* __restrict__ g_b1,
    const void* __restrict__ g_W2,
    const void* __restrict__ g_b2,
    const void* __restrict__ g_W3,
    const void* __restrict__ g_b3,
    void* __restrict__ g_out)
{
    // dtype sniff: L_tril[0][1] is exactly 0.0f in the stored array.
    // f32 buffer  -> word 1 == 0.0f.
    // bf16 buffer -> word 1 = bytes(bf16(L[0][2]=0), bf16(L[1][0]~±0.05)) != 0.
    const bool f32 = (((const float*)g_L_tril)[1] == 0.0f);

    // per-flow staged MLP weights (fp32)
    __shared__ __align__(16) float sW2[HIDDEN * HIDDEN];  // 16 KB
    __shared__ float sW1[HIDDEN], sB1[HIDDEN], sB2[HIDDEN];
    __shared__ __align__(16) float sW3[4 * HIDDEN];
    __shared__ float sB3[4];
    // all-flow small precompute
    __shared__ float sWm[NUM_FLOWS][9];   // fused 3x3 flow matrix W
    __shared__ float sEls[NUM_FLOWS][3];  // exp(an_log_scale)
    __shared__ float sSh[NUM_FLOWS][3];   // an_shift
    __shared__ float sLc[9];              // cholesky L
    __shared__ float sMean[3];
    __shared__ float sLdBase;             // uniform log-det constant

    const int tid = threadIdx.x;

    if (tid == 0) {
        // Lt = tril(L_tril) + 1e-6 I ; cov = Lt Lt^T ; Lc = chol(cov)
        float Lt[3][3];
        for (int i = 0; i < 3; ++i)
            for (int j = 0; j < 3; ++j)
                Lt[i][j] = (j <= i) ? ldv(g_L_tril, i * 3 + j, f32) : 0.f;
        for (int i = 0; i < 3; ++i) Lt[i][i] += 1e-6f;
        float cov[3][3];
        for (int i = 0; i < 3; ++i)
            for (int j = 0; j < 3; ++j) {
                float s = 0.f;
                for (int k = 0; k < 3; ++k) s += Lt[i][k] * Lt[j][k];
                cov[i][j] = s;
            }
        float c00 = sqrtf(cov[0][0]);
        float c10 = cov[1][0] / c00, c20 = cov[2][0] / c00;
        float c11 = sqrtf(cov[1][1] - c10 * c10);
        float c21 = (cov[2][1] - c20 * c10) / c11;
        float c22 = sqrtf(cov[2][2] - c20 * c20 - c21 * c21);
        sLc[0] = c00; sLc[1] = 0.f; sLc[2] = 0.f;
        sLc[3] = c10; sLc[4] = c11; sLc[5] = 0.f;
        sLc[6] = c20; sLc[7] = c21; sLc[8] = c22;
        for (int d = 0; d < 3; ++d) sMean[d] = ldv(g_base_mean, d, f32);

        float ldb = 0.f;
        for (int f = 0; f < NUM_FLOWS; ++f) {
            for (int d = 0; d < 3; ++d) {
                float ls = ldv(g_an_log_scale, f * 3 + d, f32);
                sEls[f][d] = __expf(ls);
                sSh[f][d] = ldv(g_an_shift, f * 3 + d, f32);
                ldb += ls + ldv(g_lu_log_s, f * 3 + d, f32);
            }
            // U = triu(lu_u,1) + diag(sign_s * exp(lu_log_s)); Lm = tril(lu_l,-1)+I
            float U[3][3], Lm[3][3], M[3][3], P[3][3];
            for (int i = 0; i < 3; ++i)
                for (int j = 0; j < 3; ++j) {
                    U[i][j] = (j > i) ? ldv(g_lu_u, f * 9 + i * 3 + j, f32) : 0.f;
                    Lm[i][j] = (j < i) ? ldv(g_lu_l, f * 9 + i * 3 + j, f32) : (i == j ? 1.f : 0.f);
                    P[i][j] = ldv(g_perm_p, f * 9 + i * 3 + j, f32);
                }
            for (int i = 0; i < 3; ++i)
                U[i][i] = ldv(g_sign_s, f * 3 + i, f32) * __expf(ldv(g_lu_log_s, f * 3 + i, f32));
            for (int i = 0; i < 3; ++i)
                for (int j = 0; j < 3; ++j) {
                    float s = 0.f;
                    for (int k = 0; k < 3; ++k) s += Lm[i][k] * U[k][j];
                    M[i][j] = s;
                }
            for (int i = 0; i < 3; ++i)
                for (int j = 0; j < 3; ++j) {
                    float s = 0.f;
                    for (int k = 0; k < 3; ++k) s += P[i][k] * M[k][j];
                    sWm[f][i * 3 + j] = s;
                }
        }
        sLdBase = ldb;
    }
    __syncthreads();

    const int t = blockIdx.x * BLOCK + tid;  // 0 .. NTHREADS-1

    float z[SPT][3];
    float ld[SPT];
#pragma unroll
    for (int s = 0; s < SPT; ++s) {
        const int idx = t + s * NTHREADS;
        float e0 = ldv(g_eps, idx * 3 + 0, f32);
        float e1 = ldv(g_eps, idx * 3 + 1, f32);
        float e2 = ldv(g_eps, idx * 3 + 2, f32);
        z[s][0] = sMean[0] + sLc[0] * e0;
        z[s][1] = sMean[1] + sLc[3] * e0 + sLc[4] * e1;
        z[s][2] = sMean[2] + sLc[6] * e0 + sLc[7] * e1 + sLc[8] * e2;
        ld[s] = 0.f;
    }

    float h[SPT][HIDDEN];

    for (int f = 0; f < NUM_FLOWS; ++f) {
        __syncthreads();  // previous flow's weight consumers done
        // stage flow-f weights into LDS as fp32
        for (int i = tid; i < HIDDEN * HIDDEN; i += BLOCK) sW2[i] = ldv(g_W2, f * HIDDEN * HIDDEN + i, f32);
        for (int i = tid; i < HIDDEN; i += BLOCK) {
            sW1[i] = ldv(g_W1, f * HIDDEN + i, f32);
            sB1[i] = ldv(g_b1, f * HIDDEN + i, f32);
            sB2[i] = ldv(g_b2, f * HIDDEN + i, f32);
        }
        for (int i = tid; i < 4 * HIDDEN; i += BLOCK) sW3[i] = ldv(g_W3, f * 4 * HIDDEN + i, f32);
        if (tid < 4) sB3[tid] = ldv(g_b3, f * 4 + tid, f32);
        __syncthreads();

        float wm[9];
#pragma unroll
        for (int i = 0; i < 9; ++i) wm[i] = sWm[f][i];

        float o0[SPT], o1[SPT], o2[SPT], o3[SPT];
#pragma unroll
        for (int s = 0; s < SPT; ++s) {
            // actnorm + invertible-1x1 fused affine
            float t0 = sEls[f][0] * (z[s][0] + sSh[f][0]);
            float t1 = sEls[f][1] * (z[s][1] + sSh[f][1]);
            float t2 = sEls[f][2] * (z[s][2] + sSh[f][2]);
            float zn0 = wm[0] * t0 + wm[1] * t1 + wm[2] * t2;
            float zn1 = wm[3] * t0 + wm[4] * t1 + wm[5] * t2;
            float zn2 = wm[6] * t0 + wm[7] * t1 + wm[8] * t2;
            z[s][0] = zn0; z[s][1] = zn1; z[s][2] = zn2;
            // layer 1: h = relu(z1 * w1 + b1)
#pragma unroll
            for (int k = 0; k < HIDDEN; ++k)
                h[s][k] = fmaxf(fmaf(zn0, sW1[k], sB1[k]), 0.f);
            o0[s] = sB3[0]; o1[s] = sB3[1]; o2[s] = sB3[2]; o3[s] = sB3[3];
        }

        // layer 2 + 3 fused: per output-neuron j, dot(W2[j,:],h) -> relu -> W3 accum
        const float4* __restrict__ W2v = (const float4*)sW2;
#pragma unroll 2
        for (int j = 0; j < HIDDEN; ++j) {
            const float4* __restrict__ row = W2v + j * (HIDDEN / 4);
            float bj = sB2[j];
            float a0a = bj, a0b = 0.f, a1a = bj, a1b = 0.f;
#pragma unroll
            for (int q = 0; q < 8; ++q) {
                float4 wA = row[2 * q];
                float4 wB = row[2 * q + 1];
                const int k = 8 * q;
                a0a = fmaf(wA.x, h[0][k + 0], a0a);
                a0a = fmaf(wA.y, h[0][k + 1], a0a);
                a0a = fmaf(wA.z, h[0][k + 2], a0a);
                a0a = fmaf(wA.w, h[0][k + 3], a0a);
                a0b = fmaf(wB.x, h[0][k + 4], a0b);
                a0b = fmaf(wB.y, h[0][k + 5], a0b);
                a0b = fmaf(wB.z, h[0][k + 6], a0b);
                a0b = fmaf(wB.w, h[0][k + 7], a0b);
                a1a = fmaf(wA.x, h[1][k + 0], a1a);
                a1a = fmaf(wA.y, h[1][k + 1], a1a);
                a1a = fmaf(wA.z, h[1][k + 2], a1a);
                a1a = fmaf(wA.w, h[1][k + 3], a1a);
                a1b = fmaf(wB.x, h[1][k + 4], a1b);
                a1b = fmaf(wB.y, h[1][k + 5], a1b);
                a1b = fmaf(wB.z, h[1][k + 6], a1b);
                a1b = fmaf(wB.w, h[1][k + 7], a1b);
            }
            float h20 = fmaxf(a0a + a0b, 0.f);
            float h21 = fmaxf(a1a + a1b, 0.f);
            float w30 = sW3[0 * HIDDEN + j];
            float w31 = sW3[1 * HIDDEN + j];
            float w32 = sW3[2 * HIDDEN + j];
            float w33 = sW3[3 * HIDDEN + j];
            o0[0] = fmaf(w30, h20, o0[0]);
            o1[0] = fmaf(w31, h20, o1[0]);
            o2[0] = fmaf(w32, h20, o2[0]);
            o3[0] = fmaf(w33, h20, o3[0]);
            o0[1] = fmaf(w30, h21, o0[1]);
            o1[1] = fmaf(w31, h21, o1[1]);
            o2[1] = fmaf(w32, h21, o2[1]);
            o3[1] = fmaf(w33, h21, o3[1]);
        }

#pragma unroll
        for (int s = 0; s < SPT; ++s) {
            float es2 = __expf(o2[s]);
            float es3 = __expf(o3[s]);
            z[s][1] = fmaf(z[s][1], es2, o0[s]);
            z[s][2] = fmaf(z[s][2], es3, o1[s]);
            ld[s] += o2[s] + o3[s];
        }
    }

    const float ldBase = sLdBase;
#pragma unroll
    for (int s = 0; s < SPT; ++s) {
        const int idx = t + s * NTHREADS;
        stv(g_out, idx * 3 + 0, z[s][0], f32);
        stv(g_out, idx * 3 + 1, __expf(z[s][1]), f32);
        stv(g_out, idx * 3 + 2, __expf(z[s][2]), f32);
        stv(g_out, 3 * N_SAMPLES + idx, ld[s] + ldBase + z[s][1] + z[s][2], f32);
    }
}

extern "C" void kernel_launch(void* const* d_in, const int* in_sizes, int n_in,
                              void* d_out, int out_size, void* d_ws, size_t ws_size,
                              hipStream_t stream) {
    glow_kernel<<<dim3(NBLOCKS), dim3(BLOCK), 0, stream>>>(
        d_in[0],   // eps
        d_in[1],   // L_tril
        d_in[2],   // base_mean
        d_in[3],   // an_log_scale
        d_in[4],   // an_shift
        d_in[5],   // perm_p
        d_in[6],   // sign_s
        d_in[7],   // lu_l
        d_in[8],   // lu_u
        d_in[9],   // lu_log_s
        d_in[10],  // W1
        d_in[11],  // b1
        d_in[12],  // W2
        d_in[13],  // b2
        d_in[14],  // W3
        d_in[15],  // b3
        d_out);
}

// Round 3
// 298.032 us; speedup vs baseline: 1.4516x; 1.4516x over previous
//
#include <hip/hip_runtime.h>
#include <hip/hip_bf16.h>

#define N_SAMPLES 262144
#define NUM_FLOWS 8
#define HIDDEN 64
#define BLOCK 256
#define WAVES (BLOCK / 64)
#define MT 2                                        // 16-row m-tiles per wave
#define SAMPLES_PER_WAVE (MT * 16)                  // 32
#define SAMPLES_PER_BLOCK (WAVES * SAMPLES_PER_WAVE)// 128
#define NBLOCKS (N_SAMPLES / SAMPLES_PER_BLOCK)     // 2048

typedef __attribute__((ext_vector_type(8))) short bf16x8;
typedef __attribute__((ext_vector_type(4))) float floatx4;

union FragU { bf16x8 v; __hip_bfloat16 e[8]; };

__device__ __forceinline__ float b2f(__hip_bfloat16 x) { return __bfloat162float(x); }

// dtype-flexible load/store; f32 flag is grid-uniform (sniffed from L_tril[0][1]==0).
__device__ __forceinline__ float ldv(const void* p, int i, bool f32) {
    return f32 ? ((const float*)p)[i] : b2f(((const __hip_bfloat16*)p)[i]);
}
__device__ __forceinline__ void stv(void* p, int i, float v, bool f32) {
    if (f32) ((float*)p)[i] = v;
    else ((__hip_bfloat16*)p)[i] = __float2bfloat16(v);
}

// 16-lane reduction on the VALU pipe via DPP row_ror (row = 16 lanes on CDNA).
template <int CTRL>
__device__ __forceinline__ float ror_add(float v) {
    int t = __builtin_amdgcn_update_dpp(0, __float_as_int(v), CTRL, 0xF, 0xF, true);
    return v + __int_as_float(t);
}
__device__ __forceinline__ float red16(float v) {
    v = ror_add<0x128>(v);  // row_ror:8
    v = ror_add<0x124>(v);  // row_ror:4
    v = ror_add<0x122>(v);  // row_ror:2
    v = ror_add<0x121>(v);  // row_ror:1
    return v;               // all 16 lanes of the row hold the sum
}

__global__ __launch_bounds__(BLOCK, 2) void glow_kernel(
    const void* __restrict__ g_eps,
    const void* __restrict__ g_L_tril,
    const void* __restrict__ g_base_mean,
    const void* __restrict__ g_an_log_scale,
    const void* __restrict__ g_an_shift,
    const void* __restrict__ g_perm_p,
    const void* __restrict__ g_sign_s,
    const void* __restrict__ g_lu_l,
    const void* __restrict__ g_lu_u,
    const void* __restrict__ g_lu_log_s,
    const void* __restrict__ g_W1,
    const void* __restrict__ g_b1,
    const void* __restrict__ g_W2,
    const void* __restrict__ g_b2,
    const void* __restrict__ g_W3,
    const void* __restrict__ g_b3,
    void* __restrict__ g_out)
{
    const bool f32 = (((const float*)g_L_tril)[1] == 0.0f);

    // per-flow staged weights
    __shared__ __align__(16) __hip_bfloat16 sW2f[4096];   // W2 in B-frag order, 8 KB
    __shared__ __align__(16) float sW1[HIDDEN], sB1[HIDDEN], sB2[HIDDEN];
    __shared__ __align__(16) float sW3t[HIDDEN * 4];      // [j][o]
    __shared__ __align__(16) float sB3[4];
    // all-flow precompute
    __shared__ __align__(16) float sConst[NUM_FLOWS][16]; // wm[9], els[3], sh[3], pad
    __shared__ __align__(16) float sLc[12];
    __shared__ float sMean[3];
    __shared__ float sLdBase;
    __shared__ __align__(16) float sEps[SAMPLES_PER_BLOCK * 3];
    __shared__ __align__(16) float sZx[WAVES * SAMPLES_PER_WAVE];

    const int tid  = threadIdx.x;
    const int lane = tid & 63;
    const int wave = tid >> 6;
    const int quad = lane >> 4;
    const int col  = lane & 15;

    if (tid == 0) {
        float Lt[3][3];
        for (int i = 0; i < 3; ++i)
            for (int j = 0; j < 3; ++j)
                Lt[i][j] = (j <= i) ? ldv(g_L_tril, i * 3 + j, f32) : 0.f;
        for (int i = 0; i < 3; ++i) Lt[i][i] += 1e-6f;
        float cov[3][3];
        for (int i = 0; i < 3; ++i)
            for (int j = 0; j < 3; ++j) {
                float s = 0.f;
                for (int k = 0; k < 3; ++k) s += Lt[i][k] * Lt[j][k];
                cov[i][j] = s;
            }
        float c00 = sqrtf(cov[0][0]);
        float c10 = cov[1][0] / c00, c20 = cov[2][0] / c00;
        float c11 = sqrtf(cov[1][1] - c10 * c10);
        float c21 = (cov[2][1] - c20 * c10) / c11;
        float c22 = sqrtf(cov[2][2] - c20 * c20 - c21 * c21);
        sLc[0] = c00; sLc[3] = c10; sLc[4] = c11;
        sLc[6] = c20; sLc[7] = c21; sLc[8] = c22;
        for (int d = 0; d < 3; ++d) sMean[d] = ldv(g_base_mean, d, f32);

        float ldb = 0.f;
        for (int f = 0; f < NUM_FLOWS; ++f) {
            for (int d = 0; d < 3; ++d) {
                float ls = ldv(g_an_log_scale, f * 3 + d, f32);
                sConst[f][9 + d]  = __expf(ls);
                sConst[f][12 + d] = ldv(g_an_shift, f * 3 + d, f32);
                ldb += ls + ldv(g_lu_log_s, f * 3 + d, f32);
            }
            float U[3][3], Lm[3][3], M[3][3], P[3][3];
            for (int i = 0; i < 3; ++i)
                for (int j = 0; j < 3; ++j) {
                    U[i][j]  = (j > i) ? ldv(g_lu_u, f * 9 + i * 3 + j, f32) : 0.f;
                    Lm[i][j] = (j < i) ? ldv(g_lu_l, f * 9 + i * 3 + j, f32) : (i == j ? 1.f : 0.f);
                    P[i][j]  = ldv(g_perm_p, f * 9 + i * 3 + j, f32);
                }
            for (int i = 0; i < 3; ++i)
                U[i][i] = ldv(g_sign_s, f * 3 + i, f32) * __expf(ldv(g_lu_log_s, f * 3 + i, f32));
            for (int i = 0; i < 3; ++i)
                for (int j = 0; j < 3; ++j) {
                    float s = 0.f;
                    for (int k = 0; k < 3; ++k) s += Lm[i][k] * U[k][j];
                    M[i][j] = s;
                }
            for (int i = 0; i < 3; ++i)
                for (int j = 0; j < 3; ++j) {
                    float s = 0.f;
                    for (int k = 0; k < 3; ++k) s += P[i][k] * M[k][j];
                    sConst[f][i * 3 + j] = s;
                }
            sConst[f][15] = 0.f;
        }
        sLdBase = ldb;
    }
    // stage eps for this block
    for (int i = tid; i < SAMPLES_PER_BLOCK * 3; i += BLOCK)
        sEps[i] = ldv(g_eps, blockIdx.x * SAMPLES_PER_BLOCK * 3 + i, f32);
    __syncthreads();

    // z init: z = mean + eps @ Lc^T  (lane owns samples m = mt*16 + quad*4 + r, replicated over col)
    float zc0[MT][4], zc1[MT][4], zc2[MT][4], ldacc[MT][4];
    {
        float l00 = sLc[0], l10 = sLc[3], l11 = sLc[4];
        float l20 = sLc[6], l21 = sLc[7], l22 = sLc[8];
        float m0 = sMean[0], m1 = sMean[1], m2 = sMean[2];
#pragma unroll
        for (int mt = 0; mt < MT; ++mt)
#pragma unroll
            for (int r = 0; r < 4; ++r) {
                int sl = wave * 32 + mt * 16 + quad * 4 + r;
                float e0 = sEps[sl * 3 + 0];
                float e1 = sEps[sl * 3 + 1];
                float e2 = sEps[sl * 3 + 2];
                zc0[mt][r] = m0 + l00 * e0;
                zc1[mt][r] = m1 + l10 * e0 + l11 * e1;
                zc2[mt][r] = m2 + l20 * e0 + l21 * e1 + l22 * e2;
                ldacc[mt][r] = 0.f;
            }
    }

    for (int f = 0; f < NUM_FLOWS; ++f) {
        __syncthreads();
        // ---- stage flow-f weights ----
#pragma unroll
        for (int t = 0; t < 16; ++t) {          // W2 -> bf16 B-fragment order
            int idx = tid + t * BLOCK;          // 0..4095
            int fr = idx >> 9, rem = idx & 511;
            int L = rem >> 3, j = rem & 7;
            int kc = fr >> 2, nt = fr & 3;
            int k = kc * 32 + (L >> 4) * 8 + j;
            int n = nt * 16 + (L & 15);
            sW2f[idx] = __float2bfloat16(ldv(g_W2, f * 4096 + n * 64 + k, f32));
        }
        {   // W3 transposed: sW3t[j*4+o] = W3[o][j]
            int n = tid >> 2, o = tid & 3;
            sW3t[tid] = ldv(g_W3, f * 256 + o * 64 + n, f32);
        }
        if (tid < 64) {
            sW1[tid] = ldv(g_W1, f * 64 + tid, f32);
            sB1[tid] = ldv(g_b1, f * 64 + tid, f32);
            sB2[tid] = ldv(g_b2, f * 64 + tid, f32);
            if (tid < 4) sB3[tid] = ldv(g_b3, f * 4 + tid, f32);
        }
        __syncthreads();

        // ---- per-flow constants & B fragments ----
        const floatx4* cp = (const floatx4*)sConst[f];
        floatx4 c0 = cp[0], c1 = cp[1], c2 = cp[2], c3 = cp[3];
        bf16x8 Bf[2][4];
#pragma unroll
        for (int kc = 0; kc < 2; ++kc)
#pragma unroll
            for (int nt = 0; nt < 4; ++nt)
                Bf[kc][nt] = *(const bf16x8*)&sW2f[((kc * 4 + nt) * 64 + lane) * 8];

        // ---- actnorm + 1x1 affine (fp32) ----
#pragma unroll
        for (int mt = 0; mt < MT; ++mt)
#pragma unroll
            for (int r = 0; r < 4; ++r) {
                float t0 = c2[1] * (zc0[mt][r] + c3[0]);
                float t1 = c2[2] * (zc1[mt][r] + c3[1]);
                float t2 = c2[3] * (zc2[mt][r] + c3[2]);
                float n0 = c0[0] * t0 + c0[1] * t1 + c0[2] * t2;
                float n1 = c0[3] * t0 + c1[0] * t1 + c1[1] * t2;
                float n2 = c1[2] * t0 + c1[3] * t1 + c2[0] * t2;
                zc0[mt][r] = n0; zc1[mt][r] = n1; zc2[mt][r] = n2;
            }

        // ---- z1 redistribution: row-layout -> A-layout (m = col) via tiny LDS ----
        if (col == 0) {
#pragma unroll
            for (int mt = 0; mt < MT; ++mt) {
                floatx4 w = {zc0[mt][0], zc0[mt][1], zc0[mt][2], zc0[mt][3]};
                *(floatx4*)&sZx[wave * 32 + mt * 16 + quad * 4] = w;
            }
        }
        float z0A[MT];
#pragma unroll
        for (int mt = 0; mt < MT; ++mt)
            z0A[mt] = sZx[wave * 32 + mt * 16 + col];

        // ---- layer 1 (rank-1, fp32) -> bf16 A fragments ----
        FragU hA[MT][2];
#pragma unroll
        for (int kc = 0; kc < 2; ++kc) {
            const floatx4* w1p = (const floatx4*)&sW1[kc * 32 + quad * 8];
            const floatx4* b1p = (const floatx4*)&sB1[kc * 32 + quad * 8];
            floatx4 w1a = w1p[0], w1b = w1p[1];
            floatx4 b1a = b1p[0], b1b = b1p[1];
#pragma unroll
            for (int mt = 0; mt < MT; ++mt) {
                float z0 = z0A[mt];
#pragma unroll
                for (int j = 0; j < 4; ++j) {
                    hA[mt][kc].e[j]     = __float2bfloat16(fmaxf(fmaf(z0, w1a[j], b1a[j]), 0.f));
                    hA[mt][kc].e[4 + j] = __float2bfloat16(fmaxf(fmaf(z0, w1b[j], b1b[j]), 0.f));
                }
            }
        }

        // ---- layer 2 (MFMA) + layer-3 partials ----
        float po[MT][4][4];
#pragma unroll
        for (int mt = 0; mt < MT; ++mt)
#pragma unroll
            for (int o = 0; o < 4; ++o)
#pragma unroll
                for (int r = 0; r < 4; ++r) po[mt][o][r] = 0.f;

#pragma unroll
        for (int nt = 0; nt < 4; ++nt) {
            float b2v = sB2[nt * 16 + col];
            floatx4 w3v = *(const floatx4*)&sW3t[(nt * 16 + col) * 4];
#pragma unroll
            for (int mt = 0; mt < MT; ++mt) {
                floatx4 acc = {0.f, 0.f, 0.f, 0.f};
                acc = __builtin_amdgcn_mfma_f32_16x16x32_bf16(hA[mt][0].v, Bf[0][nt], acc, 0, 0, 0);
                acc = __builtin_amdgcn_mfma_f32_16x16x32_bf16(hA[mt][1].v, Bf[1][nt], acc, 0, 0, 0);
#pragma unroll
                for (int r = 0; r < 4; ++r) {
                    float h2 = fmaxf(acc[r] + b2v, 0.f);
                    po[mt][0][r] = fmaf(w3v[0], h2, po[mt][0][r]);
                    po[mt][1][r] = fmaf(w3v[1], h2, po[mt][1][r]);
                    po[mt][2][r] = fmaf(w3v[2], h2, po[mt][2][r]);
                    po[mt][3][r] = fmaf(w3v[3], h2, po[mt][3][r]);
                }
            }
        }

        // ---- reduce over j (the col dimension) -> results land in row layout ----
#pragma unroll
        for (int mt = 0; mt < MT; ++mt)
#pragma unroll
            for (int o = 0; o < 4; ++o)
#pragma unroll
                for (int r = 0; r < 4; ++r)
                    po[mt][o][r] = red16(po[mt][o][r]);

        float b30 = sB3[0], b31 = sB3[1], b32 = sB3[2], b33 = sB3[3];
#pragma unroll
        for (int mt = 0; mt < MT; ++mt)
#pragma unroll
            for (int r = 0; r < 4; ++r) {
                float sh0 = po[mt][0][r] + b30;
                float sh1 = po[mt][1][r] + b31;
                float ls0 = po[mt][2][r] + b32;
                float ls1 = po[mt][3][r] + b33;
                zc1[mt][r] = fmaf(zc1[mt][r], __expf(ls0), sh0);
                zc2[mt][r] = fmaf(zc2[mt][r], __expf(ls1), sh1);
                ldacc[mt][r] += ls0 + ls1;
            }
    }

    const float ldBase = sLdBase;
    if (col == 0) {
#pragma unroll
        for (int mt = 0; mt < MT; ++mt)
#pragma unroll
            for (int r = 0; r < 4; ++r) {
                int g = blockIdx.x * SAMPLES_PER_BLOCK + wave * 32 + mt * 16 + quad * 4 + r;
                stv(g_out, g * 3 + 0, zc0[mt][r], f32);
                stv(g_out, g * 3 + 1, __expf(zc1[mt][r]), f32);
                stv(g_out, g * 3 + 2, __expf(zc2[mt][r]), f32);
                stv(g_out, 3 * N_SAMPLES + g, ldacc[mt][r] + ldBase + zc1[mt][r] + zc2[mt][r], f32);
            }
    }
}

extern "C" void kernel_launch(void* const* d_in, const int* in_sizes, int n_in,
                              void* d_out, int out_size, void* d_ws, size_t ws_size,
                              hipStream_t stream) {
    glow_kernel<<<dim3(NBLOCKS), dim3(BLOCK), 0, stream>>>(
        d_in[0], d_in[1], d_in[2], d_in[3], d_in[4], d_in[5], d_in[6], d_in[7],
        d_in[8], d_in[9], d_in[10], d_in[11], d_in[12], d_in[13], d_in[14], d_in[15],
        d_out);
}

// Round 4
// 188.947 us; speedup vs baseline: 2.2896x; 1.5773x over previous
//
#include <hip/hip_runtime.h>
#include <hip/hip_bf16.h>

#define N_SAMPLES 262144
#define NUM_FLOWS 8
#define BLOCK 256
#define WAVES 4
#define MT 2                                   // 16-row m-tiles per wave
#define CHUNK 128                              // samples per block per chunk
#define NCHUNK 4
#define SAMPLES_PER_BLOCK (CHUNK * NCHUNK)     // 512
#define NBLOCKS (N_SAMPLES / SAMPLES_PER_BLOCK)// 512 = 2 blocks/CU exactly

typedef __attribute__((ext_vector_type(8))) short bf16x8;
typedef __attribute__((ext_vector_type(4))) short shortx4;
typedef __attribute__((ext_vector_type(4))) float floatx4;

union FragU { bf16x8 v; __hip_bfloat16 e[8]; };
union S4U   { shortx4 v; __hip_bfloat16 e[4]; };

__device__ __forceinline__ float b2f(__hip_bfloat16 x) { return __bfloat162float(x); }

// dtype-flexible load/store; f32 flag is grid-uniform (sniffed from L_tril[0][1]==0).
__device__ __forceinline__ float ldv(const void* p, int i, bool f32) {
    return f32 ? ((const float*)p)[i] : b2f(((const __hip_bfloat16*)p)[i]);
}
__device__ __forceinline__ void stv(void* p, int i, float v, bool f32) {
    if (f32) ((float*)p)[i] = v;
    else ((__hip_bfloat16*)p)[i] = __float2bfloat16(v);
}

// 16-lane reduction on the VALU pipe via DPP row_ror (row = 16 lanes).
template <int CTRL>
__device__ __forceinline__ float ror_add(float v) {
    int t = __builtin_amdgcn_update_dpp(0, __float_as_int(v), CTRL, 0xF, 0xF, true);
    return v + __int_as_float(t);
}
__device__ __forceinline__ float red16(float v) {
    v = ror_add<0x128>(v);
    v = ror_add<0x124>(v);
    v = ror_add<0x122>(v);
    v = ror_add<0x121>(v);
    return v;  // all 16 lanes of the row hold the sum
}

__global__ __launch_bounds__(BLOCK, 2) void glow_kernel(
    const void* __restrict__ g_eps,
    const void* __restrict__ g_L_tril,
    const void* __restrict__ g_base_mean,
    const void* __restrict__ g_an_log_scale,
    const void* __restrict__ g_an_shift,
    const void* __restrict__ g_perm_p,
    const void* __restrict__ g_sign_s,
    const void* __restrict__ g_lu_l,
    const void* __restrict__ g_lu_u,
    const void* __restrict__ g_lu_log_s,
    const void* __restrict__ g_W1,
    const void* __restrict__ g_b1,
    const void* __restrict__ g_W2,
    const void* __restrict__ g_b2,
    const void* __restrict__ g_W3,
    const void* __restrict__ g_b3,
    void* __restrict__ g_out)
{
    const bool f32 = (((const float*)g_L_tril)[1] == 0.0f);

    // ---- all-flow staged weights (one-time) ----
    __shared__ __align__(16) __hip_bfloat16 sW2f[NUM_FLOWS * 4096]; // 64 KB, frag order
    __shared__ __align__(16) float sW1a[512], sB1a[512], sB2a[512]; // 6 KB
    __shared__ __align__(16) __hip_bfloat16 sW3t[NUM_FLOWS * 256];  // 4 KB, [f][j][o]
    __shared__ __align__(16) float sB3a[32];
    __shared__ __align__(16) float sConst[NUM_FLOWS][16]; // wm[9], els[3], sh[3], ldb
    __shared__ __align__(16) float sLc[12];
    __shared__ float sMean[4];
    __shared__ __align__(16) float sZx[WAVES * 32];       // per-wave z1 exchange

    const int tid  = threadIdx.x;
    const int lane = tid & 63;
    const int wave = tid >> 6;
    const int quad = lane >> 4;
    const int col  = lane & 15;

    // ---- distributed small precompute ----
    if (tid < NUM_FLOWS) {
        const int f = tid;
        float ldb = 0.f;
        for (int d = 0; d < 3; ++d) {
            float ls = ldv(g_an_log_scale, f * 3 + d, f32);
            sConst[f][9 + d]  = __expf(ls);
            sConst[f][12 + d] = ldv(g_an_shift, f * 3 + d, f32);
            ldb += ls + ldv(g_lu_log_s, f * 3 + d, f32);
        }
        float U[3][3], Lm[3][3], M[3][3], P[3][3];
        for (int i = 0; i < 3; ++i)
            for (int j = 0; j < 3; ++j) {
                U[i][j]  = (j > i) ? ldv(g_lu_u, f * 9 + i * 3 + j, f32) : 0.f;
                Lm[i][j] = (j < i) ? ldv(g_lu_l, f * 9 + i * 3 + j, f32) : (i == j ? 1.f : 0.f);
                P[i][j]  = ldv(g_perm_p, f * 9 + i * 3 + j, f32);
            }
        for (int i = 0; i < 3; ++i)
            U[i][i] = ldv(g_sign_s, f * 3 + i, f32) * __expf(ldv(g_lu_log_s, f * 3 + i, f32));
        for (int i = 0; i < 3; ++i)
            for (int j = 0; j < 3; ++j) {
                float s = 0.f;
                for (int k = 0; k < 3; ++k) s += Lm[i][k] * U[k][j];
                M[i][j] = s;
            }
        for (int i = 0; i < 3; ++i)
            for (int j = 0; j < 3; ++j) {
                float s = 0.f;
                for (int k = 0; k < 3; ++k) s += P[i][k] * M[k][j];
                sConst[f][i * 3 + j] = s;
            }
        sConst[f][15] = ldb;
    } else if (tid == 8) {
        float Lt[3][3];
        for (int i = 0; i < 3; ++i)
            for (int j = 0; j < 3; ++j)
                Lt[i][j] = (j <= i) ? ldv(g_L_tril, i * 3 + j, f32) : 0.f;
        for (int i = 0; i < 3; ++i) Lt[i][i] += 1e-6f;
        float cov[3][3];
        for (int i = 0; i < 3; ++i)
            for (int j = 0; j < 3; ++j) {
                float s = 0.f;
                for (int k = 0; k < 3; ++k) s += Lt[i][k] * Lt[j][k];
                cov[i][j] = s;
            }
        float c00 = sqrtf(cov[0][0]);
        float c10 = cov[1][0] / c00, c20 = cov[2][0] / c00;
        float c11 = sqrtf(cov[1][1] - c10 * c10);
        float c21 = (cov[2][1] - c20 * c10) / c11;
        float c22 = sqrtf(cov[2][2] - c20 * c20 - c21 * c21);
        sLc[0] = c00; sLc[3] = c10; sLc[4] = c11;
        sLc[6] = c20; sLc[7] = c21; sLc[8] = c22;
        for (int d = 0; d < 3; ++d) sMean[d] = ldv(g_base_mean, d, f32);
    }

    // ---- W2: coalesced 16B read -> bf16 frag-scatter LDS write (all flows) ----
    // element (f, n, k) -> sW2f[((f*8 + (k>>5)*4 + (n>>4))*64 + ((k>>3)&3)*16 + (n&15))*8 + (k&7)]
    if (f32) {
        const float4* src = (const float4*)g_W2;
        for (int i4 = tid; i4 < 8192; i4 += BLOCK) {
            float4 v = src[i4];
            int e = i4 << 2;
            int fl = e >> 12, n = (e >> 6) & 63, k = e & 63;
            int dst = ((fl * 8 + (k >> 5) * 4 + (n >> 4)) * 64 + ((k >> 3) & 3) * 16 + (n & 15)) * 8 + (k & 7);
            S4U u;
            u.e[0] = __float2bfloat16(v.x);
            u.e[1] = __float2bfloat16(v.y);
            u.e[2] = __float2bfloat16(v.z);
            u.e[3] = __float2bfloat16(v.w);
            *(shortx4*)&sW2f[dst] = u.v;
        }
    } else {
        const shortx4* src = (const shortx4*)g_W2;
        for (int i4 = tid; i4 < 8192; i4 += BLOCK) {
            shortx4 v = src[i4];
            int e = i4 << 2;
            int fl = e >> 12, n = (e >> 6) & 63, k = e & 63;
            int dst = ((fl * 8 + (k >> 5) * 4 + (n >> 4)) * 64 + ((k >> 3) & 3) * 16 + (n & 15)) * 8 + (k & 7);
            *(shortx4*)&sW2f[dst] = v;
        }
    }
    // W3 -> transposed bf16 [f][j][o]
    for (int i = tid; i < 2048; i += BLOCK) {
        int fl = i >> 8, r = i & 255, o = r >> 6, n = r & 63;
        sW3t[fl * 256 + n * 4 + o] = __float2bfloat16(ldv(g_W3, i, f32));
    }
    for (int i = tid; i < 512; i += BLOCK) {
        sW1a[i] = ldv(g_W1, i, f32);
        sB1a[i] = ldv(g_b1, i, f32);
        sB2a[i] = ldv(g_b2, i, f32);
    }
    if (tid < 32) sB3a[tid] = ldv(g_b3, tid, f32);

    __syncthreads();  // the ONLY barrier

    float ldBase = 0.f;
#pragma unroll
    for (int f = 0; f < NUM_FLOWS; ++f) ldBase += sConst[f][15];
    const float l00 = sLc[0], l10 = sLc[3], l11 = sLc[4];
    const float l20 = sLc[6], l21 = sLc[7], l22 = sLc[8];
    const float m0 = sMean[0], m1 = sMean[1], m2 = sMean[2];

#pragma unroll 1
    for (int chunk = 0; chunk < NCHUNK; ++chunk) {
        const int base = blockIdx.x * SAMPLES_PER_BLOCK + chunk * CHUNK + wave * 32;

        float zc0[MT][4], zc1[MT][4], zc2[MT][4], ldacc[MT][4];
#pragma unroll
        for (int mt = 0; mt < MT; ++mt)
#pragma unroll
            for (int r = 0; r < 4; ++r) {
                int g = base + mt * 16 + quad * 4 + r;  // replicated over col -> HW broadcast
                float e0 = ldv(g_eps, g * 3 + 0, f32);
                float e1 = ldv(g_eps, g * 3 + 1, f32);
                float e2 = ldv(g_eps, g * 3 + 2, f32);
                zc0[mt][r] = m0 + l00 * e0;
                zc1[mt][r] = m1 + l10 * e0 + l11 * e1;
                zc2[mt][r] = m2 + l20 * e0 + l21 * e1 + l22 * e2;
                ldacc[mt][r] = 0.f;
            }

#pragma unroll 1
        for (int f = 0; f < NUM_FLOWS; ++f) {
            const floatx4* cp = (const floatx4*)sConst[f];
            floatx4 c0 = cp[0], c1 = cp[1], c2 = cp[2], c3 = cp[3];

            // actnorm + 1x1 affine (fp32)
#pragma unroll
            for (int mt = 0; mt < MT; ++mt)
#pragma unroll
                for (int r = 0; r < 4; ++r) {
                    float t0 = c2[1] * (zc0[mt][r] + c3[0]);
                    float t1 = c2[2] * (zc1[mt][r] + c3[1]);
                    float t2 = c2[3] * (zc2[mt][r] + c3[2]);
                    float n0 = c0[0] * t0 + c0[1] * t1 + c0[2] * t2;
                    float n1 = c0[3] * t0 + c1[0] * t1 + c1[1] * t2;
                    float n2 = c1[2] * t0 + c1[3] * t1 + c2[0] * t2;
                    zc0[mt][r] = n0; zc1[mt][r] = n1; zc2[mt][r] = n2;
                }

            // z1: row-layout -> A-layout via per-wave LDS (same-wave ordering, no barrier)
            if (col == 0) {
#pragma unroll
                for (int mt = 0; mt < MT; ++mt) {
                    floatx4 w = {zc0[mt][0], zc0[mt][1], zc0[mt][2], zc0[mt][3]};
                    *(floatx4*)&sZx[wave * 32 + mt * 16 + quad * 4] = w;
                }
            }
            float z0A[MT];
#pragma unroll
            for (int mt = 0; mt < MT; ++mt)
                z0A[mt] = sZx[wave * 32 + mt * 16 + col];

            // layer 1 (rank-1, fp32) -> bf16 A fragments
            FragU hA[MT][2];
#pragma unroll
            for (int kc = 0; kc < 2; ++kc) {
                const floatx4* w1p = (const floatx4*)&sW1a[f * 64 + kc * 32 + quad * 8];
                const floatx4* b1p = (const floatx4*)&sB1a[f * 64 + kc * 32 + quad * 8];
                floatx4 w1a = w1p[0], w1b = w1p[1];
                floatx4 b1a = b1p[0], b1b = b1p[1];
#pragma unroll
                for (int mt = 0; mt < MT; ++mt) {
                    float z0 = z0A[mt];
#pragma unroll
                    for (int j = 0; j < 4; ++j) {
                        hA[mt][kc].e[j]     = __float2bfloat16(fmaxf(fmaf(z0, w1a[j], b1a[j]), 0.f));
                        hA[mt][kc].e[4 + j] = __float2bfloat16(fmaxf(fmaf(z0, w1b[j], b1b[j]), 0.f));
                    }
                }
            }

            // B fragments for this flow
            bf16x8 Bf[2][4];
#pragma unroll
            for (int kc = 0; kc < 2; ++kc)
#pragma unroll
                for (int nt = 0; nt < 4; ++nt)
                    Bf[kc][nt] = *(const bf16x8*)&sW2f[f * 4096 + ((kc * 4 + nt) * 64 + lane) * 8];

            // layer 2 (MFMA) + layer-3 partials
            float po[MT][4][4];
#pragma unroll
            for (int mt = 0; mt < MT; ++mt)
#pragma unroll
                for (int o = 0; o < 4; ++o)
#pragma unroll
                    for (int r = 0; r < 4; ++r) po[mt][o][r] = 0.f;

#pragma unroll
            for (int nt = 0; nt < 4; ++nt) {
                float b2v = sB2a[f * 64 + nt * 16 + col];
                S4U w3u;
                w3u.v = *(const shortx4*)&sW3t[f * 256 + (nt * 16 + col) * 4];
                float w30 = b2f(w3u.e[0]), w31 = b2f(w3u.e[1]);
                float w32 = b2f(w3u.e[2]), w33 = b2f(w3u.e[3]);
#pragma unroll
                for (int mt = 0; mt < MT; ++mt) {
                    floatx4 acc = {0.f, 0.f, 0.f, 0.f};
                    acc = __builtin_amdgcn_mfma_f32_16x16x32_bf16(hA[mt][0].v, Bf[0][nt], acc, 0, 0, 0);
                    acc = __builtin_amdgcn_mfma_f32_16x16x32_bf16(hA[mt][1].v, Bf[1][nt], acc, 0, 0, 0);
#pragma unroll
                    for (int r = 0; r < 4; ++r) {
                        float h2 = fmaxf(acc[r] + b2v, 0.f);
                        po[mt][0][r] = fmaf(w30, h2, po[mt][0][r]);
                        po[mt][1][r] = fmaf(w31, h2, po[mt][1][r]);
                        po[mt][2][r] = fmaf(w32, h2, po[mt][2][r]);
                        po[mt][3][r] = fmaf(w33, h2, po[mt][3][r]);
                    }
                }
            }

            // reduce over col -> results land in row layout (replicated over col)
#pragma unroll
            for (int mt = 0; mt < MT; ++mt)
#pragma unroll
                for (int o = 0; o < 4; ++o)
#pragma unroll
                    for (int r = 0; r < 4; ++r)
                        po[mt][o][r] = red16(po[mt][o][r]);

            float b30 = sB3a[f * 4 + 0], b31 = sB3a[f * 4 + 1];
            float b32 = sB3a[f * 4 + 2], b33 = sB3a[f * 4 + 3];
#pragma unroll
            for (int mt = 0; mt < MT; ++mt)
#pragma unroll
                for (int r = 0; r < 4; ++r) {
                    float sh0 = po[mt][0][r] + b30;
                    float sh1 = po[mt][1][r] + b31;
                    float ls0 = po[mt][2][r] + b32;
                    float ls1 = po[mt][3][r] + b33;
                    zc1[mt][r] = fmaf(zc1[mt][r], __expf(ls0), sh0);
                    zc2[mt][r] = fmaf(zc2[mt][r], __expf(ls1), sh1);
                    ldacc[mt][r] += ls0 + ls1;
                }
        }

        if (col == 0) {
#pragma unroll
            for (int mt = 0; mt < MT; ++mt)
#pragma unroll
                for (int r = 0; r < 4; ++r) {
                    int g = base + mt * 16 + quad * 4 + r;
                    stv(g_out, g * 3 + 0, zc0[mt][r], f32);
                    stv(g_out, g * 3 + 1, __expf(zc1[mt][r]), f32);
                    stv(g_out, g * 3 + 2, __expf(zc2[mt][r]), f32);
                    stv(g_out, 3 * N_SAMPLES + g, ldacc[mt][r] + ldBase + zc1[mt][r] + zc2[mt][r], f32);
                }
        }
    }
}

extern "C" void kernel_launch(void* const* d_in, const int* in_sizes, int n_in,
                              void* d_out, int out_size, void* d_ws, size_t ws_size,
                              hipStream_t stream) {
    glow_kernel<<<dim3(NBLOCKS), dim3(BLOCK), 0, stream>>>(
        d_in[0], d_in[1], d_in[2], d_in[3], d_in[4], d_in[5], d_in[6], d_in[7],
        d_in[8], d_in[9], d_in[10], d_in[11], d_in[12], d_in[13], d_in[14], d_in[15],
        d_out);
}

// Round 5
// 161.293 us; speedup vs baseline: 2.6822x; 1.1715x over previous
//
#include <hip/hip_runtime.h>
#include <hip/hip_bf16.h>

#define N_SAMPLES 262144
#define NUM_FLOWS 8
#define BLOCK 256
#define WAVES 4
#define MT 2                                    // 16-sample col-tiles per wave
#define CHUNK 128                               // samples per block per chunk
#define NCHUNK 2
#define SAMPLES_PER_BLOCK (CHUNK * NCHUNK)      // 256
#define NBLOCKS (N_SAMPLES / SAMPLES_PER_BLOCK) // 1024 -> 4 blocks/CU resident

typedef __attribute__((ext_vector_type(8))) short bf16x8;
typedef __attribute__((ext_vector_type(4))) short shortx4;
typedef __attribute__((ext_vector_type(4))) float floatx4;

union FragU { bf16x8 v; __hip_bfloat16 e[8]; };
union S4U   { shortx4 v; __hip_bfloat16 e[4]; };

__device__ __forceinline__ float b2f(__hip_bfloat16 x) { return __bfloat162float(x); }

// dtype-flexible load/store; f32 flag is grid-uniform (sniffed from L_tril[0][1]==0).
__device__ __forceinline__ float ldv(const void* p, int i, bool f32) {
    return f32 ? ((const float*)p)[i] : b2f(((const __hip_bfloat16*)p)[i]);
}
__device__ __forceinline__ void stv(void* p, int i, float v, bool f32) {
    if (f32) ((float*)p)[i] = v;
    else ((__hip_bfloat16*)p)[i] = __float2bfloat16(v);
}

__global__ __launch_bounds__(BLOCK, 4) void glow_kernel(
    const void* __restrict__ g_eps,
    const void* __restrict__ g_L_tril,
    const void* __restrict__ g_base_mean,
    const void* __restrict__ g_an_log_scale,
    const void* __restrict__ g_an_shift,
    const void* __restrict__ g_perm_p,
    const void* __restrict__ g_sign_s,
    const void* __restrict__ g_lu_l,
    const void* __restrict__ g_lu_u,
    const void* __restrict__ g_lu_log_s,
    const void* __restrict__ g_W1,
    const void* __restrict__ g_b1,
    const void* __restrict__ g_W2,
    const void* __restrict__ g_b2,
    const void* __restrict__ g_W3,
    const void* __restrict__ g_b3,
    void* __restrict__ g_out)
{
    const bool f32 = (((const float*)g_L_tril)[1] == 0.0f);

    // ---- group-staged weights (4 flows per group), ~40 KB total ----
    __shared__ __align__(16) __hip_bfloat16 sW2f[4 * 4096];  // 32 KB, frag order
    __shared__ __align__(16) float sW1a[256], sB1a[256], sB2a[256]; // 3 KB
    __shared__ __align__(16) float sW3f[4 * 256];            // 4 KB, [fi][j][o]
    __shared__ __align__(16) float sB3a[32];                 // all 8 flows
    __shared__ __align__(16) float sConst[NUM_FLOWS][16];    // wm[9], els[3], sh[3], ldb
    __shared__ __align__(16) float sLc[12];
    __shared__ float sMean[4];

    const int tid  = threadIdx.x;
    const int lane = tid & 63;
    const int wave = tid >> 6;
    const int quad = lane >> 4;
    const int col  = lane & 15;

    // ---- distributed small precompute (once) ----
    if (tid < NUM_FLOWS) {
        const int f = tid;
        float ldb = 0.f;
        for (int d = 0; d < 3; ++d) {
            float ls = ldv(g_an_log_scale, f * 3 + d, f32);
            sConst[f][9 + d]  = __expf(ls);
            sConst[f][12 + d] = ldv(g_an_shift, f * 3 + d, f32);
            ldb += ls + ldv(g_lu_log_s, f * 3 + d, f32);
        }
        float U[3][3], Lm[3][3], M[3][3], P[3][3];
        for (int i = 0; i < 3; ++i)
            for (int j = 0; j < 3; ++j) {
                U[i][j]  = (j > i) ? ldv(g_lu_u, f * 9 + i * 3 + j, f32) : 0.f;
                Lm[i][j] = (j < i) ? ldv(g_lu_l, f * 9 + i * 3 + j, f32) : (i == j ? 1.f : 0.f);
                P[i][j]  = ldv(g_perm_p, f * 9 + i * 3 + j, f32);
            }
        for (int i = 0; i < 3; ++i)
            U[i][i] = ldv(g_sign_s, f * 3 + i, f32) * __expf(ldv(g_lu_log_s, f * 3 + i, f32));
        for (int i = 0; i < 3; ++i)
            for (int j = 0; j < 3; ++j) {
                float s = 0.f;
                for (int k = 0; k < 3; ++k) s += Lm[i][k] * U[k][j];
                M[i][j] = s;
            }
        for (int i = 0; i < 3; ++i)
            for (int j = 0; j < 3; ++j) {
                float s = 0.f;
                for (int k = 0; k < 3; ++k) s += P[i][k] * M[k][j];
                sConst[f][i * 3 + j] = s;
            }
        sConst[f][15] = ldb;
    } else if (tid == 8) {
        float Lt[3][3];
        for (int i = 0; i < 3; ++i)
            for (int j = 0; j < 3; ++j)
                Lt[i][j] = (j <= i) ? ldv(g_L_tril, i * 3 + j, f32) : 0.f;
        for (int i = 0; i < 3; ++i) Lt[i][i] += 1e-6f;
        float cov[3][3];
        for (int i = 0; i < 3; ++i)
            for (int j = 0; j < 3; ++j) {
                float s = 0.f;
                for (int k = 0; k < 3; ++k) s += Lt[i][k] * Lt[j][k];
                cov[i][j] = s;
            }
        float c00 = sqrtf(cov[0][0]);
        float c10 = cov[1][0] / c00, c20 = cov[2][0] / c00;
        float c11 = sqrtf(cov[1][1] - c10 * c10);
        float c21 = (cov[2][1] - c20 * c10) / c11;
        float c22 = sqrtf(cov[2][2] - c20 * c20 - c21 * c21);
        sLc[0] = c00; sLc[3] = c10; sLc[4] = c11;
        sLc[6] = c20; sLc[7] = c21; sLc[8] = c22;
        for (int d = 0; d < 3; ++d) sMean[d] = ldv(g_base_mean, d, f32);
    }
    if (tid < 32) sB3a[tid] = ldv(g_b3, tid, f32);

    // persistent per-sample state (col layout: sample = base + mt*16 + col,
    // replicated over the 4 quads)
    float zc0[NCHUNK][MT], zc1[NCHUNK][MT], zc2[NCHUNK][MT], lda[NCHUNK][MT];
    float ldBase = 0.f;

#pragma unroll
    for (int grp = 0; grp < 2; ++grp) {
        if (grp) __syncthreads();  // all reads of previous group's LDS done

        // ---- stage this group's 4 flows ----
        // W2 -> bf16 frag order: elem (fl,n,k) -> [((fl*8 + (k>>5)*4 + (n>>4))*64
        //                                + ((k>>3)&3)*16 + (n&15))*8 + (k&7)]
        if (f32) {
            const float4* src = (const float4*)g_W2 + grp * 4096;
            for (int i4 = tid; i4 < 4096; i4 += BLOCK) {
                float4 v = src[i4];
                int e = i4 << 2;
                int fl = e >> 12, n = (e >> 6) & 63, k = e & 63;
                int dst = ((fl * 8 + (k >> 5) * 4 + (n >> 4)) * 64 + ((k >> 3) & 3) * 16 + (n & 15)) * 8 + (k & 7);
                S4U u;
                u.e[0] = __float2bfloat16(v.x);
                u.e[1] = __float2bfloat16(v.y);
                u.e[2] = __float2bfloat16(v.z);
                u.e[3] = __float2bfloat16(v.w);
                *(shortx4*)&sW2f[dst] = u.v;
            }
        } else {
            const shortx4* src = (const shortx4*)g_W2 + grp * 4096;
            for (int i4 = tid; i4 < 4096; i4 += BLOCK) {
                shortx4 v = src[i4];
                int e = i4 << 2;
                int fl = e >> 12, n = (e >> 6) & 63, k = e & 63;
                int dst = ((fl * 8 + (k >> 5) * 4 + (n >> 4)) * 64 + ((k >> 3) & 3) * 16 + (n & 15)) * 8 + (k & 7);
                *(shortx4*)&sW2f[dst] = v;
            }
        }
        {   // W3 -> fp32 transposed [fi][j][o]
            int i = tid;
            for (int it = 0; it < 4; ++it, i += BLOCK) {
                int fl = i >> 8, r = i & 255, o = r >> 6, n = r & 63;
                sW3f[fl * 256 + n * 4 + o] = ldv(g_W3, (grp * 4 + fl) * 256 + r, f32);
            }
        }
        {   // W1/b1/b2 fp32
            int fl = tid >> 6, k = tid & 63;
            int gi = (grp * 4 + fl) * 64 + k;
            sW1a[tid] = ldv(g_W1, gi, f32);
            sB1a[tid] = ldv(g_b1, gi, f32);
            sB2a[tid] = ldv(g_b2, gi, f32);
        }
        __syncthreads();

        if (grp == 0) {
#pragma unroll
            for (int f = 0; f < NUM_FLOWS; ++f) ldBase += sConst[f][15];
        }

#pragma unroll
        for (int chunk = 0; chunk < NCHUNK; ++chunk) {
            const int base = blockIdx.x * SAMPLES_PER_BLOCK + chunk * CHUNK + wave * 32;

            if (grp == 0) {
                const float l00 = sLc[0], l10 = sLc[3], l11 = sLc[4];
                const float l20 = sLc[6], l21 = sLc[7], l22 = sLc[8];
                const float m0 = sMean[0], m1 = sMean[1], m2 = sMean[2];
#pragma unroll
                for (int mt = 0; mt < MT; ++mt) {
                    int g = base + mt * 16 + col;  // 4-way quad-replicated -> HW broadcast
                    float e0 = ldv(g_eps, g * 3 + 0, f32);
                    float e1 = ldv(g_eps, g * 3 + 1, f32);
                    float e2 = ldv(g_eps, g * 3 + 2, f32);
                    zc0[chunk][mt] = m0 + l00 * e0;
                    zc1[chunk][mt] = m1 + l10 * e0 + l11 * e1;
                    zc2[chunk][mt] = m2 + l20 * e0 + l21 * e1 + l22 * e2;
                    lda[chunk][mt] = 0.f;
                }
            }

#pragma unroll 1
            for (int fi = 0; fi < 4; ++fi) {
                const int f = grp * 4 + fi;
                const floatx4* cp = (const floatx4*)sConst[f];
                floatx4 c0 = cp[0], c1 = cp[1], c2 = cp[2], c3 = cp[3];

                // actnorm + 1x1 affine (fp32), 2 slots
#pragma unroll
                for (int mt = 0; mt < MT; ++mt) {
                    float t0 = c2[1] * (zc0[chunk][mt] + c3[0]);
                    float t1 = c2[2] * (zc1[chunk][mt] + c3[1]);
                    float t2 = c2[3] * (zc2[chunk][mt] + c3[2]);
                    zc0[chunk][mt] = c0[0] * t0 + c0[1] * t1 + c0[2] * t2;
                    zc1[chunk][mt] = c0[3] * t0 + c1[0] * t1 + c1[1] * t2;
                    zc2[chunk][mt] = c1[2] * t0 + c1[3] * t1 + c2[0] * t2;
                }

                // layer 1 -> bf16 B fragments: h[k = kc*32+quad*8+i][m = col]
                FragU hB[MT][2];
#pragma unroll
                for (int kc = 0; kc < 2; ++kc) {
                    const floatx4* w1p = (const floatx4*)&sW1a[fi * 64 + kc * 32 + quad * 8];
                    const floatx4* b1p = (const floatx4*)&sB1a[fi * 64 + kc * 32 + quad * 8];
                    floatx4 w1a = w1p[0], w1b = w1p[1];
                    floatx4 b1a = b1p[0], b1b = b1p[1];
#pragma unroll
                    for (int mt = 0; mt < MT; ++mt) {
                        float z0 = zc0[chunk][mt];
#pragma unroll
                        for (int j = 0; j < 4; ++j) {
                            hB[mt][kc].e[j]     = __float2bfloat16(fmaxf(fmaf(z0, w1a[j], b1a[j]), 0.f));
                            hB[mt][kc].e[4 + j] = __float2bfloat16(fmaxf(fmaf(z0, w1b[j], b1b[j]), 0.f));
                        }
                    }
                }

                // layer 2: h2^T = W2 @ h^T (A = W2 frags, B = h frags), b2 in acc-init
                // then layer-3 per-lane partials over this lane's 16 neurons
                float po[MT][4];
#pragma unroll
                for (int mt = 0; mt < MT; ++mt)
#pragma unroll
                    for (int o = 0; o < 4; ++o) po[mt][o] = 0.f;

#pragma unroll
                for (int jt = 0; jt < 4; ++jt) {
                    bf16x8 A0 = *(const bf16x8*)&sW2f[fi * 4096 + ((0 * 4 + jt) * 64 + lane) * 8];
                    bf16x8 A1 = *(const bf16x8*)&sW2f[fi * 4096 + ((1 * 4 + jt) * 64 + lane) * 8];
                    floatx4 b2q = *(const floatx4*)&sB2a[fi * 64 + jt * 16 + quad * 4];
                    floatx4 w3q[4];
#pragma unroll
                    for (int r = 0; r < 4; ++r)
                        w3q[r] = *(const floatx4*)&sW3f[fi * 256 + (jt * 16 + quad * 4 + r) * 4];
#pragma unroll
                    for (int mt = 0; mt < MT; ++mt) {
                        floatx4 acc = b2q;
                        acc = __builtin_amdgcn_mfma_f32_16x16x32_bf16(A0, hB[mt][0].v, acc, 0, 0, 0);
                        acc = __builtin_amdgcn_mfma_f32_16x16x32_bf16(A1, hB[mt][1].v, acc, 0, 0, 0);
#pragma unroll
                        for (int r = 0; r < 4; ++r) {
                            float h2 = fmaxf(acc[r], 0.f);
                            po[mt][0] = fmaf(w3q[r][0], h2, po[mt][0]);
                            po[mt][1] = fmaf(w3q[r][1], h2, po[mt][1]);
                            po[mt][2] = fmaf(w3q[r][2], h2, po[mt][2]);
                            po[mt][3] = fmaf(w3q[r][3], h2, po[mt][3]);
                        }
                    }
                }

                // reduce over the 4 quads (each quad holds 16 of the 64 neurons)
#pragma unroll
                for (int mt = 0; mt < MT; ++mt)
#pragma unroll
                    for (int o = 0; o < 4; ++o) {
                        float v = po[mt][o];
                        v += __shfl_xor(v, 16);
                        v += __shfl_xor(v, 32);
                        po[mt][o] = v;
                    }

                float b30 = sB3a[f * 4 + 0], b31 = sB3a[f * 4 + 1];
                float b32 = sB3a[f * 4 + 2], b33 = sB3a[f * 4 + 3];
#pragma unroll
                for (int mt = 0; mt < MT; ++mt) {
                    float sh0 = po[mt][0] + b30;
                    float sh1 = po[mt][1] + b31;
                    float ls0 = po[mt][2] + b32;
                    float ls1 = po[mt][3] + b33;
                    zc1[chunk][mt] = fmaf(zc1[chunk][mt], __expf(ls0), sh0);
                    zc2[chunk][mt] = fmaf(zc2[chunk][mt], __expf(ls1), sh1);
                    lda[chunk][mt] += ls0 + ls1;
                }
            }

            if (grp == 1 && quad == 0) {
#pragma unroll
                for (int mt = 0; mt < MT; ++mt) {
                    int g = base + mt * 16 + col;
                    float z1 = zc1[chunk][mt], z2 = zc2[chunk][mt];
                    stv(g_out, g * 3 + 0, zc0[chunk][mt], f32);
                    stv(g_out, g * 3 + 1, __expf(z1), f32);
                    stv(g_out, g * 3 + 2, __expf(z2), f32);
                    stv(g_out, 3 * N_SAMPLES + g, lda[chunk][mt] + ldBase + z1 + z2, f32);
                }
            }
        }
    }
}

extern "C" void kernel_launch(void* const* d_in, const int* in_sizes, int n_in,
                              void* d_out, int out_size, void* d_ws, size_t ws_size,
                              hipStream_t stream) {
    glow_kernel<<<dim3(NBLOCKS), dim3(BLOCK), 0, stream>>>(
        d_in[0], d_in[1], d_in[2], d_in[3], d_in[4], d_in[5], d_in[6], d_in[7],
        d_in[8], d_in[9], d_in[10], d_in[11], d_in[12], d_in[13], d_in[14], d_in[15],
        d_out);
}